// Round 5
// baseline (1036.968 us; speedup 1.0000x reference)
//
#include <hip/hip_runtime.h>

// Asym_Attention on MI355X (gfx950) — round 5 (= round-4 resubmit; infra failure).
// Pipeline: [convert f32->bf16] [gemm_bf16 128^2 m97: qkv] [attn: no-LDS no-barrier]
//           [gemm_bf16 128^2 m97: proj]
// ws (u16): Ah(37.75M, reused as oh) | Bh(1.77M) | Ph(0.59M) | q|k|vT (3x37.75M) = 306.7 MB

typedef unsigned short u16;
typedef unsigned int   u32;
typedef float f32x4 __attribute__((ext_vector_type(4)));
typedef short bfrag  __attribute__((ext_vector_type(8)));   // 8 bf16 (4 VGPRs)

__device__ __forceinline__ f32x4 mfma16(bfrag a, bfrag b, f32x4 c) {
  return __builtin_amdgcn_mfma_f32_16x16x32_bf16(a, b, c, 0, 0, 0);
}
__device__ __forceinline__ u16 bf16_rn(float f) {
  u32 u = __builtin_bit_cast(u32, f);
  return (u16)((u + 0x7fffu + ((u >> 16) & 1u)) >> 16);
}
__device__ __forceinline__ u32 pack_rn(float a, float b) {
  u32 ua = __builtin_bit_cast(u32, a), ub = __builtin_bit_cast(u32, b);
  ua = (ua + 0x7fffu + ((ua >> 16) & 1u)) >> 16;
  ub = (ub + 0x7fffu + ((ub >> 16) & 1u)) & 0xffff0000u;
  return ua | ub;
}
__device__ __forceinline__ void gll16(const u16* g, u16* l) {
  __builtin_amdgcn_global_load_lds((const __attribute__((address_space(1))) void*)g,
                                   (__attribute__((address_space(3))) void*)l, 16, 0, 0);
}

// ---------------- convert: f32 -> bf16 (rn) ----------------
__global__ __launch_bounds__(256)
void convert_kernel(const float* __restrict__ xv, const float* __restrict__ xi,
                    const float* __restrict__ wq, const float* __restrict__ wp,
                    u16* __restrict__ Ah, u16* __restrict__ Bh, u16* __restrict__ Ph) {
  const size_t NA = (size_t)49152 * 768, NB = (size_t)2304 * 768, NP = (size_t)768 * 768;
  const size_t HALF = (size_t)24576 * 768;
  size_t tid = (size_t)blockIdx.x * 256 + threadIdx.x;
  size_t stride = (size_t)gridDim.x * 256;
  for (size_t i = tid; i < NA / 8; i += stride) {
    size_t e = i * 8;
    const float* s = (e < HALF) ? (xv + e) : (xi + (e - HALF));
    float4 a = ((const float4*)s)[0], b = ((const float4*)s)[1];
    ((uint4*)Ah)[i] = make_uint4(pack_rn(a.x, a.y), pack_rn(a.z, a.w),
                                 pack_rn(b.x, b.y), pack_rn(b.z, b.w));
  }
  for (size_t i = tid; i < NB / 8; i += stride) {
    float4 a = ((const float4*)(wq + i * 8))[0], b = ((const float4*)(wq + i * 8))[1];
    ((uint4*)Bh)[i] = make_uint4(pack_rn(a.x, a.y), pack_rn(a.z, a.w),
                                 pack_rn(b.x, b.y), pack_rn(b.z, b.w));
  }
  for (size_t i = tid; i < NP / 8; i += stride) {
    float4 a = ((const float4*)(wp + i * 8))[0], b = ((const float4*)(wp + i * 8))[1];
    ((uint4*)Ph)[i] = make_uint4(pack_rn(a.x, a.y), pack_rn(a.z, a.w),
                                 pack_rn(b.x, b.y), pack_rn(b.z, b.w));
  }
}

// ---------------- bf16 GEMM, m97 structure (round-2 known-good) ----------------
template <int EPI, int NBLK>
__global__ __launch_bounds__(256, 3)
void gemm_bf16(const u16* __restrict__ Ag, const u16* __restrict__ Bg,
               const float* __restrict__ bias,
               u16* __restrict__ qo, u16* __restrict__ ko, u16* __restrict__ vo,
               float* __restrict__ outp) {
  __shared__ u16 AT[128 * 64];
  __shared__ u16 BT[128 * 64];

  const int cpx = gridDim.x >> 3;
  const int bid = (blockIdx.x & 7) * cpx + (blockIdx.x >> 3);
  const int nb = bid % NBLK, mb = bid / NBLK;
  const int t = threadIdx.x;
  const int lane = t & 63;
  const int wv = t >> 6, wm = wv >> 1, wn = wv & 1;
  const int l15 = lane & 15, lg = lane >> 4;

  const int lr = lane >> 3;                 // row within 8-row group
  const int gs = (lane & 7) ^ lr;           // pre-swizzled source granule
  const u16* asrc = Ag + ((size_t)(mb * 128 + wv * 32 + lr)) * 768 + gs * 8;
  const u16* bsrc = Bg + ((size_t)(nb * 128 + wv * 32 + lr)) * 768 + gs * 8;

  f32x4 acc[4][4];
#pragma unroll
  for (int i = 0; i < 4; i++)
#pragma unroll
    for (int j = 0; j < 4; j++) acc[i][j] = (f32x4){0.f, 0.f, 0.f, 0.f};

  for (int k0 = 0; k0 < 768; k0 += 64) {
#pragma unroll
    for (int i = 0; i < 4; i++) {
      gll16(asrc + (size_t)i * 8 * 768 + k0, AT + (wv * 32 + i * 8) * 64);
      gll16(bsrc + (size_t)i * 8 * 768 + k0, BT + (wv * 32 + i * 8) * 64);
    }
    __syncthreads();

#pragma unroll
    for (int ks = 0; ks < 2; ks++) {
      bfrag af[4], bf[4];
#pragma unroll
      for (int ms = 0; ms < 4; ms++) {
        int row = wm * 64 + ms * 16 + l15;
        af[ms] = *(const bfrag*)&AT[row * 64 + (((ks * 4 + lg) ^ (row & 7)) * 8)];
      }
#pragma unroll
      for (int ns = 0; ns < 4; ns++) {
        int row = wn * 64 + ns * 16 + l15;
        bf[ns] = *(const bfrag*)&BT[row * 64 + (((ks * 4 + lg) ^ (row & 7)) * 8)];
      }
#pragma unroll
      for (int ms = 0; ms < 4; ms++)
#pragma unroll
        for (int ns = 0; ns < 4; ns++)
          acc[ms][ns] = mfma16(af[ms], bf[ns], acc[ms][ns]);
    }
    __syncthreads();
  }

#pragma unroll
  for (int ms = 0; ms < 4; ms++) {
#pragma unroll
    for (int ns = 0; ns < 4; ns++) {
      int n = nb * 128 + wn * 64 + ns * 16 + l15;
      float bv = bias[n];
#pragma unroll
      for (int r = 0; r < 4; r++) {
        int m = mb * 128 + wm * 64 + ms * 16 + lg * 4 + r;
        float f = acc[ms][ns][r] + bv;
        if constexpr (EPI == 0) {
          int which = n / 768;
          int hh = (n % 768) / 64;
          int d = n % 64;
          int b2i = m / 384, tok = m % 384;
          int bhn = b2i * 12 + hh;
          if (which == 0) {
            qo[((size_t)bhn * 384 + tok) * 64 + d] = bf16_rn(f * 0.125f);  // fold softmax scale
          } else if (which == 1) {
            ko[((size_t)bhn * 384 + tok) * 64 + d] = bf16_rn(f);
          } else {
            vo[((size_t)bhn * 64 + d) * 384 + tok] = bf16_rn(f);           // V transposed
          }
        } else {
          outp[(size_t)m * 768 + n] = f;
        }
      }
    }
  }
}

// ---------------- flash attention: no LDS, no barriers ----------------
// One wave = 16 q-rows (block = 4 independent waves). Swapped QK^T:
// S = mfma(K_rows, Q_rows) -> lane (l15,lg) holds S[key=kt*16+lg*4+r][q=l15].
// Softmax reduces across lg group (shfl_xor 16,32). P^T B-operand built by a
// 16-shfl in-register exchange. PV: O^T = mfma(V^T_rows(d), P^T) -> lane holds
// O^T[d=dt*16+lg*4+r][q=l15]. K/V frags load DIRECTLY from global (L1/L2-resident).
__global__ __launch_bounds__(256, 3)
void attn_kernel(const u16* __restrict__ q, const u16* __restrict__ k,
                 const u16* __restrict__ vT, u16* __restrict__ oh) {
  const int cpx = gridDim.x >> 3;
  const int bid = (blockIdx.x & 7) * cpx + (blockIdx.x >> 3);
  const int qb = bid % 6, bh = bid / 6;
  const int b2i = bh / 12, hh = bh % 12;
  const int q0 = qb * 64;
  const int t = threadIdx.x;
  const int lane = t & 63, wv = t >> 6;
  const int l15 = lane & 15, lg = lane >> 4;

  const u16* qp = q + ((size_t)bh * 384 + q0 + wv * 16 + l15) * 64 + lg * 8;
  bfrag qf0 = *(const bfrag*)(qp);         // q pre-scaled by 1/8 at QKV epilogue
  bfrag qf1 = *(const bfrag*)(qp + 32);

  f32x4 o[4];
#pragma unroll
  for (int i = 0; i < 4; i++) o[i] = (f32x4){0.f, 0.f, 0.f, 0.f};
  float m_run = -1e30f, l_run = 0.f;

  const int nblk = (q0 < 128) ? 2 : 8;
  const int srcA = ((lane & 16) << 1) | l15;   // exchange source lane, words j=0,1
  const bool lo2 = (lg < 2);

  for (int kb = 0; kb < nblk; kb++) {
    int src_bh, row0;
    if (q0 < 128)      { src_bh = bh;                          row0 = kb * 64; }
    else if (kb < 2)   { src_bh = (b2i & 63) * 12 + hh;        row0 = kb * 64; }
    else if (kb < 4)   { src_bh = ((b2i & 63) + 64) * 12 + hh; row0 = (kb - 2) * 64; }
    else               { src_bh = bh;                          row0 = 128 + (kb - 4) * 64; }

    const u16* kb0 = k  + ((size_t)src_bh * 384 + row0) * 64;
    const u16* vb0 = vT + ((size_t)src_bh * 64) * 384 + row0;

    // QK^T: A = K rows (16 keys/tile), B = Q rows. K=32 mfma x2 over d=64.
    f32x4 S[4];
#pragma unroll
    for (int kt = 0; kt < 4; kt++) {
      const u16* kr = kb0 + (size_t)(kt * 16 + l15) * 64 + lg * 8;
      bfrag kf0 = *(const bfrag*)kr;
      bfrag kf1 = *(const bfrag*)(kr + 32);
      S[kt] = mfma16(kf0, qf0, (f32x4){0.f, 0.f, 0.f, 0.f});
      S[kt] = mfma16(kf1, qf1, S[kt]);
    }
    // V^T frags: issue now so they fly during softmax VALU.
    bfrag vf0[4], vf1[4];
#pragma unroll
    for (int dt = 0; dt < 4; dt++) {
      const u16* vr = vb0 + (size_t)(dt * 16 + l15) * 384 + lg * 8;
      vf0[dt] = *(const bfrag*)vr;
      vf1[dt] = *(const bfrag*)(vr + 32);
    }

    // online softmax for query l15 (stats shared by the 4 lg lanes)
    float mx = S[0][0];
#pragma unroll
    for (int kt = 0; kt < 4; kt++)
#pragma unroll
      for (int r = 0; r < 4; r++) mx = fmaxf(mx, S[kt][r]);
    mx = fmaxf(mx, __shfl_xor(mx, 16));
    mx = fmaxf(mx, __shfl_xor(mx, 32));
    float nm = fmaxf(m_run, mx);
    float fac = __expf(m_run - nm);
    m_run = nm;
    l_run *= fac;
#pragma unroll
    for (int dt = 0; dt < 4; dt++) o[dt] *= fac;

    float ps = 0.f;
    u32 w[4][2];
#pragma unroll
    for (int kt = 0; kt < 4; kt++) {
      float p0 = __expf(S[kt][0] - nm), p1 = __expf(S[kt][1] - nm);
      float p2 = __expf(S[kt][2] - nm), p3 = __expf(S[kt][3] - nm);
      ps += (p0 + p1) + (p2 + p3);
      w[kt][0] = pack_rn(p0, p1);
      w[kt][1] = pack_rn(p2, p3);
    }
    ps += __shfl_xor(ps, 16);
    ps += __shfl_xor(ps, 32);
    l_run += ps;

    // exchange: build P^T B-operand frags (keys 0..31 and 32..63).
    // dest word j <- lane srcA+16*(j>>1), value w[kt][j&1], kt = (lg>>1) (+2 for tile1)
    union { bfrag v; u32 u[4]; } P0, P1;
#pragma unroll
    for (int j = 0; j < 4; j++) {
      int s = srcA + ((j >> 1) << 4);
      int sel = j & 1;
      int a0 = __shfl((int)w[0][sel], s);
      int a1 = __shfl((int)w[1][sel], s);
      int a2 = __shfl((int)w[2][sel], s);
      int a3 = __shfl((int)w[3][sel], s);
      P0.u[j] = (u32)(lo2 ? a0 : a1);
      P1.u[j] = (u32)(lo2 ? a2 : a3);
    }

    // PV: O^T[d][q] accumulate
#pragma unroll
    for (int dt = 0; dt < 4; dt++) {
      o[dt] = mfma16(vf0[dt], P0.v, o[dt]);
      o[dt] = mfma16(vf1[dt], P1.v, o[dt]);
    }
  }

  float inv = 1.f / l_run;
  int tok = q0 + wv * 16 + l15;
  u16* ob = oh + ((size_t)b2i * 384 + tok) * 768 + hh * 64 + lg * 4;
#pragma unroll
  for (int dt = 0; dt < 4; dt++) {
    u32 w0 = pack_rn(o[dt][0] * inv, o[dt][1] * inv);
    u32 w1 = pack_rn(o[dt][2] * inv, o[dt][3] * inv);
    *(uint2*)(ob + dt * 16) = make_uint2(w0, w1);
  }
}

extern "C" void kernel_launch(void* const* d_in, const int* in_sizes, int n_in,
                              void* d_out, int out_size, void* d_ws, size_t ws_size,
                              hipStream_t stream) {
  const float* xv    = (const float*)d_in[0];
  const float* xi    = (const float*)d_in[1];
  const float* wqkv  = (const float*)d_in[2];
  const float* bqkv  = (const float*)d_in[3];
  const float* wproj = (const float*)d_in[4];
  const float* bproj = (const float*)d_in[5];
  float* outp = (float*)d_out;

  const size_t SZ = (size_t)1536 * 384 * 64;   // 37,748,736 u16
  const size_t NB = (size_t)2304 * 768;
  const size_t NP = (size_t)768 * 768;
  const size_t WS_NEED = (SZ + NB + NP + 3 * SZ) * sizeof(u16);  // 306,708,480 B
  if (ws_size < WS_NEED) {
    hipMemsetAsync(d_out, 0, (size_t)out_size * sizeof(float), stream);
    return;
  }
  u16* Ah = (u16*)d_ws;          // reused as oh after QKV gemm
  u16* Bh = Ah + SZ;
  u16* Ph = Bh + NB;
  u16* q_ = Ph + NP;
  u16* k_ = q_ + SZ;
  u16* v_ = k_ + SZ;
  u16* oh = Ah;

  convert_kernel<<<dim3(1024), 256, 0, stream>>>(xv, xi, wqkv, wproj, Ah, Bh, Ph);
  gemm_bf16<0, 18><<<dim3(384 * 18), 256, 0, stream>>>(Ah, Bh, bqkv, q_, k_, v_, nullptr);
  attn_kernel<<<dim3(1536 * 6), 256, 0, stream>>>(q_, k_, v_, oh);
  gemm_bf16<1, 6><<<dim3(384 * 6), 256, 0, stream>>>(oh, Ph, bproj, nullptr, nullptr, nullptr, outp);
}